// Round 2
// baseline (694.720 us; speedup 1.0000x reference)
//
#include <hip/hip_runtime.h>
#include <hip/hip_bf16.h>
#include <stdint.h>

#define NN 100000
#define NE 1600000
#define IND 512
#define HID 128
#define OUTD 64
#define BN_EPS 1e-5f
#define NBLK 391   // ceil(NN/256)

// ---------------- edge dtype probe -----------------------------------------
// If edge_index arrived as int64, every odd int32 word (high half) is 0.
// If int32, odd words are random node ids (P(zero)=1e-5 each).
__global__ void k_detect(const int* __restrict__ e, int* __restrict__ flag) {
  __shared__ int nz;
  if (threadIdx.x == 0) nz = 0;
  __syncthreads();
  int v = e[2 * threadIdx.x + 1];  // 64 threads -> first 64 odd words
  if (v != 0) atomicAdd(&nz, 1);
  __syncthreads();
  if (threadIdx.x == 0) *flag = (nz == 0) ? 1 : 0;  // 1 => int64
}

__device__ __forceinline__ int edge_at(const int* e32, int f, int i) {
  if (f) return (int)((const long long*)e32)[i];
  return e32[i];
}

// ---------------- GEMM1: h1 = x @ W1  (100000x512 @ 512x128), fp32 ----------
__global__ __launch_bounds__(256) void k_gemm1(const float* __restrict__ x,
                                               const float* __restrict__ W,
                                               float* __restrict__ h1) {
  __shared__ float As[16][132];  // transposed A: As[k][m], BM=128
  __shared__ float Bs[16][132];  // Bs[k][n], BN=HID=128
  const int tid = threadIdx.x;
  const int tr = tid >> 4, tc = tid & 15;
  const int row0 = blockIdx.x * 128;
  float acc[8][8];
#pragma unroll
  for (int i = 0; i < 8; ++i)
#pragma unroll
    for (int j = 0; j < 8; ++j) acc[i][j] = 0.f;

  for (int kt = 0; kt < IND; kt += 16) {
    // A tile: 128 rows x 16 cols = 512 float4
#pragma unroll
    for (int rr = 0; rr < 2; ++rr) {
      int idx = tid + rr * 256;
      int r = idx >> 2;
      int c = (idx & 3) << 2;
      int row = row0 + r; if (row > NN - 1) row = NN - 1;
      float4 v = *(const float4*)(x + (size_t)row * IND + kt + c);
      As[c + 0][r] = v.x; As[c + 1][r] = v.y;
      As[c + 2][r] = v.z; As[c + 3][r] = v.w;
    }
    // B tile: 16 rows x 128 cols = 512 float4
#pragma unroll
    for (int rr = 0; rr < 2; ++rr) {
      int idx = tid + rr * 256;
      int kk = idx >> 5;
      int cc = (idx & 31) << 2;
      *(float4*)&Bs[kk][cc] = *(const float4*)(W + (size_t)(kt + kk) * HID + cc);
    }
    __syncthreads();
#pragma unroll
    for (int kk = 0; kk < 16; ++kk) {
      float a[8], b[8];
      *(float4*)&a[0] = *(const float4*)&As[kk][tr * 8];
      *(float4*)&a[4] = *(const float4*)&As[kk][tr * 8 + 4];
      *(float4*)&b[0] = *(const float4*)&Bs[kk][tc * 8];
      *(float4*)&b[4] = *(const float4*)&Bs[kk][tc * 8 + 4];
#pragma unroll
      for (int i = 0; i < 8; ++i)
#pragma unroll
        for (int j = 0; j < 8; ++j) acc[i][j] = fmaf(a[i], b[j], acc[i][j]);
    }
    __syncthreads();
  }
#pragma unroll
  for (int i = 0; i < 8; ++i) {
    int row = row0 + tr * 8 + i;
    if (row < NN) {
      float4 v0 = {acc[i][0], acc[i][1], acc[i][2], acc[i][3]};
      float4 v1 = {acc[i][4], acc[i][5], acc[i][6], acc[i][7]};
      *(float4*)(h1 + (size_t)row * HID + tc * 8) = v0;
      *(float4*)(h1 + (size_t)row * HID + tc * 8 + 4) = v1;
    }
  }
}

// ---------------- CSR build ------------------------------------------------
__global__ void k_count(const int* __restrict__ edges, const int* __restrict__ flag,
                        int* __restrict__ cnt) {
  int e = blockIdx.x * 256 + threadIdx.x;
  if (e < NE) {
    int f = *flag;
    atomicAdd(&cnt[edge_at(edges, f, NE + e)], 1);
  }
}

__global__ void k_s1(const int* __restrict__ cnt, int* __restrict__ bsum) {
  __shared__ int s[256];
  int tid = threadIdx.x;
  int i = blockIdx.x * 256 + tid;
  s[tid] = (i < NN) ? cnt[i] : 0;
  __syncthreads();
  for (int off = 128; off > 0; off >>= 1) {
    if (tid < off) s[tid] += s[tid + off];
    __syncthreads();
  }
  if (tid == 0) bsum[blockIdx.x] = s[0];
}

__global__ void k_s2(int* bsum) {  // 1 block, 512 threads, in-place exclusive scan
  __shared__ int s[512];
  int tid = threadIdx.x;
  int v = (tid < NBLK) ? bsum[tid] : 0;
  s[tid] = v;
  __syncthreads();
  for (int off = 1; off < 512; off <<= 1) {
    int t = (tid >= off) ? s[tid - off] : 0;
    __syncthreads();
    s[tid] += t;
    __syncthreads();
  }
  if (tid < NBLK) bsum[tid] = s[tid] - v;
}

// NOTE: cnt and cursor alias intentionally; each block reads only its own
// 256-element range before writing it (no __restrict__ here).
__global__ void k_s3(const int* cnt, const int* bsum, int* offsets, int* cursor) {
  __shared__ int s[256];
  int tid = threadIdx.x;
  int i = blockIdx.x * 256 + tid;
  int v = (i < NN) ? cnt[i] : 0;
  s[tid] = v;
  __syncthreads();
  for (int off = 1; off < 256; off <<= 1) {
    int t = (tid >= off) ? s[tid - off] : 0;
    __syncthreads();
    s[tid] += t;
    __syncthreads();
  }
  int o = bsum[blockIdx.x] + s[tid] - v;
  if (i < NN) { offsets[i] = o; cursor[i] = o; }
  if (i == 0) offsets[NN] = NE;
}

__global__ void k_scatter(const int* __restrict__ edges, const int* __restrict__ flag,
                          int* cursor, int* __restrict__ csr_src) {
  int e = blockIdx.x * 256 + threadIdx.x;
  if (e < NE) {
    int f = *flag;
    int d = edge_at(edges, f, NE + e);
    int s = edge_at(edges, f, e);
    int pos = atomicAdd(&cursor[d], 1);
    csr_src[pos] = s;
  }
}

// ---------------- Aggregation 1 (+b1): agg1[n] = sum h1[src] + b1 ----------
__global__ __launch_bounds__(256) void k_agg1(const float* __restrict__ h1,
                                              const int* __restrict__ offsets,
                                              const int* __restrict__ csr_src,
                                              const float* __restrict__ b1,
                                              float* __restrict__ agg1) {
  int w = threadIdx.x >> 6, lane = threadIdx.x & 63;
  int n = blockIdx.x * 4 + w;
  if (n >= NN) return;
  int beg = offsets[n], end = offsets[n + 1];
  const float2* h = (const float2*)h1;
  float2 acc = ((const float2*)b1)[lane];
  int i = beg;
  for (; i + 1 < end; i += 2) {
    int s0 = csr_src[i], s1 = csr_src[i + 1];
    float2 v0 = h[(size_t)s0 * 64 + lane];
    float2 v1 = h[(size_t)s1 * 64 + lane];
    acc.x += v0.x + v1.x;
    acc.y += v0.y + v1.y;
  }
  if (i < end) {
    float2 v = h[(size_t)csr_src[i] * 64 + lane];
    acc.x += v.x; acc.y += v.y;
  }
  ((float2*)agg1)[(size_t)n * 64 + lane] = acc;
}

// ---------------- BN stats -------------------------------------------------
__global__ __launch_bounds__(256) void k_bnstats(const float* __restrict__ agg1,
                                                 float* __restrict__ gsum,
                                                 float* __restrict__ gsq) {
  __shared__ float ss[256], qq[256];
  int tid = threadIdx.x;
  int col = tid & 127, half = tid >> 7;
  int r0 = blockIdx.x * 128;
  float s = 0.f, q = 0.f;
  for (int k = 0; k < 64; ++k) {
    int r = r0 + half + 2 * k;
    if (r < NN) {
      float v = agg1[(size_t)r * HID + col];
      s += v; q += v * v;
    }
  }
  ss[tid] = s; qq[tid] = q;
  __syncthreads();
  if (tid < 128) {
    atomicAdd(&gsum[tid], ss[tid] + ss[tid + 128]);
    atomicAdd(&gsq[tid], qq[tid] + qq[tid + 128]);
  }
}

__global__ void k_bnfin(const float* __restrict__ gsum, const float* __restrict__ gsq,
                        const float* __restrict__ gamma, const float* __restrict__ beta,
                        float* __restrict__ isg, float* __restrict__ bb) {
  int c = threadIdx.x;  // 128 threads
  float mean = gsum[c] * (1.f / NN);
  float var = gsq[c] * (1.f / NN) - mean * mean;
  var = fmaxf(var, 0.f);
  float inv = 1.f / sqrtf(var + BN_EPS);
  float g = gamma[c] * inv;
  isg[c] = g;
  bb[c] = beta[c] - mean * g;
}

// ---------------- GEMM2 (BN+ReLU fused on A): h2 = relu(bn(agg1)) @ W2 -----
__global__ __launch_bounds__(256) void k_gemm2(const float* __restrict__ agg1,
                                               const float* __restrict__ W2,
                                               const float* __restrict__ isg,
                                               const float* __restrict__ bb,
                                               float* __restrict__ h2) {
  __shared__ float As[32][132];  // As[k][m], BM=128, BK=32
  __shared__ float Bs[32][68];   // Bs[k][n], BN=64
  __shared__ float isgS[128], bbS[128];
  const int tid = threadIdx.x;
  if (tid < 128) { isgS[tid] = isg[tid]; bbS[tid] = bb[tid]; }
  __syncthreads();
  const int tr = tid >> 4, tc = tid & 15;
  const int row0 = blockIdx.x * 128;
  float acc[8][4];
#pragma unroll
  for (int i = 0; i < 8; ++i)
#pragma unroll
    for (int j = 0; j < 4; ++j) acc[i][j] = 0.f;

  for (int kt = 0; kt < HID; kt += 32) {
    // A tile: 128 x 32 = 1024 float4
#pragma unroll
    for (int rr = 0; rr < 4; ++rr) {
      int idx = tid + rr * 256;
      int r = idx >> 3;
      int c = (idx & 7) << 2;
      int row = row0 + r; if (row > NN - 1) row = NN - 1;
      float4 v = *(const float4*)(agg1 + (size_t)row * HID + kt + c);
      int k0 = kt + c;
      v.x = fmaxf(fmaf(v.x, isgS[k0 + 0], bbS[k0 + 0]), 0.f);
      v.y = fmaxf(fmaf(v.y, isgS[k0 + 1], bbS[k0 + 1]), 0.f);
      v.z = fmaxf(fmaf(v.z, isgS[k0 + 2], bbS[k0 + 2]), 0.f);
      v.w = fmaxf(fmaf(v.w, isgS[k0 + 3], bbS[k0 + 3]), 0.f);
      As[c + 0][r] = v.x; As[c + 1][r] = v.y;
      As[c + 2][r] = v.z; As[c + 3][r] = v.w;
    }
    // B tile: 32 x 64 = 512 float4
#pragma unroll
    for (int rr = 0; rr < 2; ++rr) {
      int idx = tid + rr * 256;
      int kk = idx >> 4;
      int cc = (idx & 15) << 2;
      *(float4*)&Bs[kk][cc] = *(const float4*)(W2 + (size_t)(kt + kk) * OUTD + cc);
    }
    __syncthreads();
#pragma unroll
    for (int kk = 0; kk < 32; ++kk) {
      float a[8], b[4];
      *(float4*)&a[0] = *(const float4*)&As[kk][tr * 8];
      *(float4*)&a[4] = *(const float4*)&As[kk][tr * 8 + 4];
      *(float4*)&b[0] = *(const float4*)&Bs[kk][tc * 4];
#pragma unroll
      for (int i = 0; i < 8; ++i)
#pragma unroll
        for (int j = 0; j < 4; ++j) acc[i][j] = fmaf(a[i], b[j], acc[i][j]);
    }
    __syncthreads();
  }
#pragma unroll
  for (int i = 0; i < 8; ++i) {
    int row = row0 + tr * 8 + i;
    if (row < NN) {
      float4 v = {acc[i][0], acc[i][1], acc[i][2], acc[i][3]};
      *(float4*)(h2 + (size_t)row * OUTD + tc * 4) = v;
    }
  }
}

// ---------------- Aggregation 2 + b2 + L2 normalize + fp32 store -----------
__global__ __launch_bounds__(256) void k_agg2norm(const float* __restrict__ h2,
                                                  const int* __restrict__ offsets,
                                                  const int* __restrict__ csr_src,
                                                  const float* __restrict__ b2,
                                                  float* __restrict__ out) {
  int w = threadIdx.x >> 6, lane = threadIdx.x & 63;
  int n = blockIdx.x * 4 + w;
  if (n >= NN) return;
  int beg = offsets[n], end = offsets[n + 1];
  float acc = b2[lane];
  int i = beg;
  for (; i + 1 < end; i += 2) {
    int s0 = csr_src[i], s1 = csr_src[i + 1];
    acc += h2[(size_t)s0 * OUTD + lane] + h2[(size_t)s1 * OUTD + lane];
  }
  if (i < end) acc += h2[(size_t)csr_src[i] * OUTD + lane];
  float q = acc * acc;
#pragma unroll
  for (int off = 32; off > 0; off >>= 1) q += __shfl_xor(q, off);
  float norm = sqrtf(q);
  float scale = 1.f / fmaxf(norm, 1e-12f);
  out[(size_t)n * OUTD + lane] = acc * scale;
}

// ---------------- launch ----------------------------------------------------
extern "C" void kernel_launch(void* const* d_in, const int* in_sizes, int n_in,
                              void* d_out, int out_size, void* d_ws, size_t ws_size,
                              hipStream_t stream) {
  const float* x     = (const float*)d_in[0];
  const int*   edges = (const int*)d_in[1];
  const float* W1    = (const float*)d_in[2];
  const float* b1    = (const float*)d_in[3];
  const float* W2    = (const float*)d_in[4];
  const float* b2    = (const float*)d_in[5];
  const float* gamma = (const float*)d_in[6];
  const float* beta  = (const float*)d_in[7];

  char* ws = (char*)d_ws;
  float* h1      = (float*)(ws);                 // 51.2 MB (reused as h2)
  float* agg1    = (float*)(ws + 51200000);      // 51.2 MB
  int*   csr_src = (int*)(ws + 102400000);       // 6.4 MB
  int*   offsets = (int*)(ws + 108800000);       // 100001 ints
  int*   cursor  = (int*)(ws + 109200128);       // aliased as cnt during build
  int*   bsum    = (int*)(ws + 109600256);       // 391 ints
  float* gsum    = (float*)(ws + 109604352);     // 128 f
  float* gsq     = (float*)(ws + 109604864);     // 128 f
  float* isg     = (float*)(ws + 109605376);     // 128 f
  float* bbv     = (float*)(ws + 109605888);     // 128 f
  int*   eflag   = (int*)(ws + 109606400);       // 1 int
  float* h2      = h1;

  if (ws_size < 109606912) return;  // scratch layout requirement

  hipMemsetAsync(cursor, 0, (NN + 1) * sizeof(int), stream);  // cnt = 0
  hipMemsetAsync(gsum, 0, 1024, stream);                      // gsum+gsq = 0

  k_detect<<<1, 64, 0, stream>>>(edges, eflag);
  k_gemm1<<<782, 256, 0, stream>>>(x, W1, h1);
  k_count<<<6250, 256, 0, stream>>>(edges, eflag, cursor);
  k_s1<<<NBLK, 256, 0, stream>>>(cursor, bsum);
  k_s2<<<1, 512, 0, stream>>>(bsum);
  k_s3<<<NBLK, 256, 0, stream>>>(cursor, bsum, offsets, cursor);
  k_scatter<<<6250, 256, 0, stream>>>(edges, eflag, cursor, csr_src);
  k_agg1<<<25000, 256, 0, stream>>>(h1, offsets, csr_src, b1, agg1);
  k_bnstats<<<782, 256, 0, stream>>>(agg1, gsum, gsq);
  k_bnfin<<<1, 128, 0, stream>>>(gsum, gsq, gamma, beta, isg, bbv);
  k_gemm2<<<782, 256, 0, stream>>>(agg1, W2, isg, bbv, h2);
  k_agg2norm<<<25000, 256, 0, stream>>>(h2, offsets, csr_src, b2,
                                        (float*)d_out);
}

// Round 3
// 554.079 us; speedup vs baseline: 1.2538x; 1.2538x over previous
//
#include <hip/hip_runtime.h>
#include <hip/hip_bf16.h>
#include <stdint.h>

#define NN 100000
#define NE 1600000
#define IND 512
#define HID 128
#define OUTD 64
#define BN_EPS 1e-5f
#define NBLK 391   // ceil(NN/256)

typedef __attribute__((ext_vector_type(8))) short short8v;
typedef __attribute__((ext_vector_type(4))) float f32x4;

// ---- fp32 -> bf16 (RNE) returning the bf16-as-fp32 value for residual ----
__device__ __forceinline__ ushort f2bf(float f, float& back) {
  uint u = __float_as_uint(f);
  uint r = u + 0x7FFFu + ((u >> 16) & 1u);
  ushort h = (ushort)(r >> 16);
  back = __uint_as_float(((uint)h) << 16);
  return h;
}
__device__ __forceinline__ float bf2f(ushort h) {
  return __uint_as_float(((uint)h) << 16);
}

// ---------------- edge dtype probe -----------------------------------------
__global__ void k_detect(const int* __restrict__ e, int* __restrict__ flag) {
  __shared__ int nz;
  if (threadIdx.x == 0) nz = 0;
  __syncthreads();
  int v = e[2 * threadIdx.x + 1];
  if (v != 0) atomicAdd(&nz, 1);
  __syncthreads();
  if (threadIdx.x == 0) *flag = (nz == 0) ? 1 : 0;  // 1 => int64
}

__device__ __forceinline__ int edge_at(const int* e32, int f, int i) {
  if (f) return (int)((const long long*)e32)[i];
  return e32[i];
}

// ---------------- W1^T split prep: Wt[n][k] hi/lo bf16 ----------------------
__global__ void k_prepW(const float* __restrict__ W1, ushort* __restrict__ Wth,
                        ushort* __restrict__ Wtl) {
  int i = blockIdx.x * 256 + threadIdx.x;  // over 128*512
  if (i >= HID * IND) return;
  int n = i >> 9, k = i & 511;
  float w = W1[(size_t)k * HID + n];
  float back, d;
  ushort h = f2bf(w, back);
  Wth[i] = h;
  Wtl[i] = f2bf(w - back, d);
}

// ---------------- GEMM1 via split-bf16 MFMA: h1b = bf16(x @ W1) -------------
// BM=128, BN=128(=HID), BK=32, 16 K-steps. 4 waves (2x2), wave tile 64x64.
__global__ __launch_bounds__(256) void k_gemm1m(const float* __restrict__ x,
                                                const ushort* __restrict__ Wth,
                                                const ushort* __restrict__ Wtl,
                                                ushort* __restrict__ h1b) {
  // LDS rows padded to 40 ushorts (80 B) -> conflict-light ds_read_b128
  __shared__ ushort sAh[128 * 40], sAl[128 * 40];
  __shared__ ushort sBh[128 * 40], sBl[128 * 40];
  const int tid = threadIdx.x;
  const int lane = tid & 63, wid = tid >> 6;
  const int wr = wid >> 1, wc = wid & 1;
  const int lrow = lane & 15, lkg = lane >> 4;
  const int row0 = blockIdx.x * 128;

  f32x4 acc[4][4];
#pragma unroll
  for (int m = 0; m < 4; ++m)
#pragma unroll
    for (int n = 0; n < 4; ++n) acc[m][n] = (f32x4){0.f, 0.f, 0.f, 0.f};

  float4 ra[4];
  uint4 rbh[2], rbl[2];

  // ---- load tile 0
#pragma unroll
  for (int i = 0; i < 4; ++i) {
    int flat = i * 256 + tid, r = flat >> 3, kq = flat & 7;
    int grow = row0 + r; if (grow > NN - 1) grow = NN - 1;
    ra[i] = *(const float4*)(x + (size_t)grow * IND + kq * 4);
  }
#pragma unroll
  for (int i = 0; i < 2; ++i) {
    int flat = i * 256 + tid, col = flat >> 2, kc = flat & 3;
    rbh[i] = *(const uint4*)(Wth + (size_t)col * IND + kc * 8);
    rbl[i] = *(const uint4*)(Wtl + (size_t)col * IND + kc * 8);
  }

  for (int s = 0; s < 16; ++s) {
    __syncthreads();  // prior step's LDS reads complete
    // ---- regs -> LDS (split A into hi/lo)
#pragma unroll
    for (int i = 0; i < 4; ++i) {
      int flat = i * 256 + tid, r = flat >> 3, kq = flat & 7;
      float bk, d;
      ushort4 hi, lo;
      hi.x = f2bf(ra[i].x, bk); lo.x = f2bf(ra[i].x - bk, d);
      hi.y = f2bf(ra[i].y, bk); lo.y = f2bf(ra[i].y - bk, d);
      hi.z = f2bf(ra[i].z, bk); lo.z = f2bf(ra[i].z - bk, d);
      hi.w = f2bf(ra[i].w, bk); lo.w = f2bf(ra[i].w - bk, d);
      *(ushort4*)&sAh[r * 40 + kq * 4] = hi;
      *(ushort4*)&sAl[r * 40 + kq * 4] = lo;
    }
#pragma unroll
    for (int i = 0; i < 2; ++i) {
      int flat = i * 256 + tid, col = flat >> 2, kc = flat & 3;
      *(uint4*)&sBh[col * 40 + kc * 8] = rbh[i];
      *(uint4*)&sBl[col * 40 + kc * 8] = rbl[i];
    }
    // ---- issue next tile's global loads (overlap with MFMA below)
    if (s < 15) {
      int kt = (s + 1) * 32;
#pragma unroll
      for (int i = 0; i < 4; ++i) {
        int flat = i * 256 + tid, r = flat >> 3, kq = flat & 7;
        int grow = row0 + r; if (grow > NN - 1) grow = NN - 1;
        ra[i] = *(const float4*)(x + (size_t)grow * IND + kt + kq * 4);
      }
#pragma unroll
      for (int i = 0; i < 2; ++i) {
        int flat = i * 256 + tid, col = flat >> 2, kc = flat & 3;
        rbh[i] = *(const uint4*)(Wth + (size_t)col * IND + kt + kc * 8);
        rbl[i] = *(const uint4*)(Wtl + (size_t)col * IND + kt + kc * 8);
      }
    }
    __syncthreads();  // LDS writes visible
    // ---- fragments + 48 MFMA
    short8v ah[4], al[4], bh[4], bl[4];
#pragma unroll
    for (int m = 0; m < 4; ++m) {
      int r = wr * 64 + m * 16 + lrow;
      ah[m] = *(const short8v*)&sAh[r * 40 + lkg * 8];
      al[m] = *(const short8v*)&sAl[r * 40 + lkg * 8];
    }
#pragma unroll
    for (int n = 0; n < 4; ++n) {
      int c = wc * 64 + n * 16 + lrow;
      bh[n] = *(const short8v*)&sBh[c * 40 + lkg * 8];
      bl[n] = *(const short8v*)&sBl[c * 40 + lkg * 8];
    }
#pragma unroll
    for (int m = 0; m < 4; ++m)
#pragma unroll
      for (int n = 0; n < 4; ++n) {
        acc[m][n] = __builtin_amdgcn_mfma_f32_16x16x32_bf16(ah[m], bh[n], acc[m][n], 0, 0, 0);
        acc[m][n] = __builtin_amdgcn_mfma_f32_16x16x32_bf16(ah[m], bl[n], acc[m][n], 0, 0, 0);
        acc[m][n] = __builtin_amdgcn_mfma_f32_16x16x32_bf16(al[m], bh[n], acc[m][n], 0, 0, 0);
      }
  }

  // ---- epilogue: store bf16 h1
#pragma unroll
  for (int m = 0; m < 4; ++m) {
    int orow0 = row0 + wr * 64 + m * 16 + (lane >> 4) * 4;
#pragma unroll
    for (int i = 0; i < 4; ++i) {
      int grow = orow0 + i;
      if (grow < NN) {
#pragma unroll
        for (int n = 0; n < 4; ++n) {
          float d;
          h1b[(size_t)grow * HID + wc * 64 + n * 16 + (lane & 15)] = f2bf(acc[m][n][i], d);
        }
      }
    }
  }
}

// ---------------- CSR build ------------------------------------------------
__global__ void k_count(const int* __restrict__ edges, const int* __restrict__ flag,
                        int* __restrict__ cnt) {
  int e = blockIdx.x * 256 + threadIdx.x;
  if (e < NE) {
    int f = *flag;
    atomicAdd(&cnt[edge_at(edges, f, NE + e)], 1);
  }
}

__global__ void k_s1(const int* __restrict__ cnt, int* __restrict__ bsum) {
  __shared__ int s[256];
  int tid = threadIdx.x;
  int i = blockIdx.x * 256 + tid;
  s[tid] = (i < NN) ? cnt[i] : 0;
  __syncthreads();
  for (int off = 128; off > 0; off >>= 1) {
    if (tid < off) s[tid] += s[tid + off];
    __syncthreads();
  }
  if (tid == 0) bsum[blockIdx.x] = s[0];
}

__global__ void k_s2(int* bsum) {
  __shared__ int s[512];
  int tid = threadIdx.x;
  int v = (tid < NBLK) ? bsum[tid] : 0;
  s[tid] = v;
  __syncthreads();
  for (int off = 1; off < 512; off <<= 1) {
    int t = (tid >= off) ? s[tid - off] : 0;
    __syncthreads();
    s[tid] += t;
    __syncthreads();
  }
  if (tid < NBLK) bsum[tid] = s[tid] - v;
}

__global__ void k_s3(const int* cnt, const int* bsum, int* offsets, int* cursor) {
  __shared__ int s[256];
  int tid = threadIdx.x;
  int i = blockIdx.x * 256 + tid;
  int v = (i < NN) ? cnt[i] : 0;
  s[tid] = v;
  __syncthreads();
  for (int off = 1; off < 256; off <<= 1) {
    int t = (tid >= off) ? s[tid - off] : 0;
    __syncthreads();
    s[tid] += t;
    __syncthreads();
  }
  int o = bsum[blockIdx.x] + s[tid] - v;
  if (i < NN) { offsets[i] = o; cursor[i] = o; }
  if (i == 0) offsets[NN] = NE;
}

__global__ void k_scatter(const int* __restrict__ edges, const int* __restrict__ flag,
                          int* cursor, int* __restrict__ csr_src) {
  int e = blockIdx.x * 256 + threadIdx.x;
  if (e < NE) {
    int f = *flag;
    int d = edge_at(edges, f, NE + e);
    int s = edge_at(edges, f, e);
    int pos = atomicAdd(&cursor[d], 1);
    csr_src[pos] = s;
  }
}

// ---------------- Aggregation 1 (+b1): agg1[n] = sum bf16 h1[src] + b1 -----
__global__ __launch_bounds__(256) void k_agg1(const ushort* __restrict__ h1b,
                                              const int* __restrict__ offsets,
                                              const int* __restrict__ csr_src,
                                              const float* __restrict__ b1,
                                              float* __restrict__ agg1) {
  int w = threadIdx.x >> 6, lane = threadIdx.x & 63;
  int n = blockIdx.x * 4 + w;
  if (n >= NN) return;
  int beg = offsets[n], end = offsets[n + 1];
  const uint* h = (const uint*)h1b;  // 2 bf16 per uint
  float2 acc = ((const float2*)b1)[lane];
  int i = beg;
  for (; i + 1 < end; i += 2) {
    uint v0 = h[(size_t)csr_src[i] * 64 + lane];
    uint v1 = h[(size_t)csr_src[i + 1] * 64 + lane];
    acc.x += __uint_as_float(v0 << 16) + __uint_as_float(v1 << 16);
    acc.y += __uint_as_float(v0 & 0xffff0000u) + __uint_as_float(v1 & 0xffff0000u);
  }
  if (i < end) {
    uint v = h[(size_t)csr_src[i] * 64 + lane];
    acc.x += __uint_as_float(v << 16);
    acc.y += __uint_as_float(v & 0xffff0000u);
  }
  ((float2*)agg1)[(size_t)n * 64 + lane] = acc;
}

// ---------------- BN stats -------------------------------------------------
__global__ __launch_bounds__(256) void k_bnstats(const float* __restrict__ agg1,
                                                 float* __restrict__ gsum,
                                                 float* __restrict__ gsq) {
  __shared__ float ss[256], qq[256];
  int tid = threadIdx.x;
  int col = tid & 127, half = tid >> 7;
  int r0 = blockIdx.x * 128;
  float s = 0.f, q = 0.f;
  for (int k = 0; k < 64; ++k) {
    int r = r0 + half + 2 * k;
    if (r < NN) {
      float v = agg1[(size_t)r * HID + col];
      s += v; q += v * v;
    }
  }
  ss[tid] = s; qq[tid] = q;
  __syncthreads();
  if (tid < 128) {
    atomicAdd(&gsum[tid], ss[tid] + ss[tid + 128]);
    atomicAdd(&gsq[tid], qq[tid] + qq[tid + 128]);
  }
}

__global__ void k_bnfin(const float* __restrict__ gsum, const float* __restrict__ gsq,
                        const float* __restrict__ gamma, const float* __restrict__ beta,
                        float* __restrict__ isg, float* __restrict__ bb) {
  int c = threadIdx.x;  // 128 threads
  float mean = gsum[c] * (1.f / NN);
  float var = gsq[c] * (1.f / NN) - mean * mean;
  var = fmaxf(var, 0.f);
  float inv = 1.f / sqrtf(var + BN_EPS);
  float g = gamma[c] * inv;
  isg[c] = g;
  bb[c] = beta[c] - mean * g;
}

// ---------------- GEMM2 (BN+ReLU fused on A): h2b = bf16(relu(bn(agg1))@W2)-
__global__ __launch_bounds__(256) void k_gemm2(const float* __restrict__ agg1,
                                               const float* __restrict__ W2,
                                               const float* __restrict__ isg,
                                               const float* __restrict__ bb,
                                               ushort* __restrict__ h2b) {
  __shared__ float As[32][132];
  __shared__ float Bs[32][68];
  __shared__ float isgS[128], bbS[128];
  const int tid = threadIdx.x;
  if (tid < 128) { isgS[tid] = isg[tid]; bbS[tid] = bb[tid]; }
  __syncthreads();
  const int tr = tid >> 4, tc = tid & 15;
  const int row0 = blockIdx.x * 128;
  float acc[8][4];
#pragma unroll
  for (int i = 0; i < 8; ++i)
#pragma unroll
    for (int j = 0; j < 4; ++j) acc[i][j] = 0.f;

  for (int kt = 0; kt < HID; kt += 32) {
#pragma unroll
    for (int rr = 0; rr < 4; ++rr) {
      int idx = tid + rr * 256;
      int r = idx >> 3;
      int c = (idx & 7) << 2;
      int row = row0 + r; if (row > NN - 1) row = NN - 1;
      float4 v = *(const float4*)(agg1 + (size_t)row * HID + kt + c);
      int k0 = kt + c;
      v.x = fmaxf(fmaf(v.x, isgS[k0 + 0], bbS[k0 + 0]), 0.f);
      v.y = fmaxf(fmaf(v.y, isgS[k0 + 1], bbS[k0 + 1]), 0.f);
      v.z = fmaxf(fmaf(v.z, isgS[k0 + 2], bbS[k0 + 2]), 0.f);
      v.w = fmaxf(fmaf(v.w, isgS[k0 + 3], bbS[k0 + 3]), 0.f);
      As[c + 0][r] = v.x; As[c + 1][r] = v.y;
      As[c + 2][r] = v.z; As[c + 3][r] = v.w;
    }
#pragma unroll
    for (int rr = 0; rr < 2; ++rr) {
      int idx = tid + rr * 256;
      int kk = idx >> 4;
      int cc = (idx & 15) << 2;
      *(float4*)&Bs[kk][cc] = *(const float4*)(W2 + (size_t)(kt + kk) * OUTD + cc);
    }
    __syncthreads();
#pragma unroll
    for (int kk = 0; kk < 32; ++kk) {
      float a[8], b[4];
      *(float4*)&a[0] = *(const float4*)&As[kk][tr * 8];
      *(float4*)&a[4] = *(const float4*)&As[kk][tr * 8 + 4];
      *(float4*)&b[0] = *(const float4*)&Bs[kk][tc * 4];
#pragma unroll
      for (int i = 0; i < 8; ++i)
#pragma unroll
        for (int j = 0; j < 4; ++j) acc[i][j] = fmaf(a[i], b[j], acc[i][j]);
    }
    __syncthreads();
  }
#pragma unroll
  for (int i = 0; i < 8; ++i) {
    int row = row0 + tr * 8 + i;
    if (row < NN) {
      float d;
      ushort4 o;
      o.x = f2bf(acc[i][0], d); o.y = f2bf(acc[i][1], d);
      o.z = f2bf(acc[i][2], d); o.w = f2bf(acc[i][3], d);
      *(ushort4*)(h2b + (size_t)row * OUTD + tc * 4) = o;
    }
  }
}

// ---------------- Aggregation 2 + b2 + L2 normalize + fp32 store -----------
__global__ __launch_bounds__(256) void k_agg2norm(const ushort* __restrict__ h2b,
                                                  const int* __restrict__ offsets,
                                                  const int* __restrict__ csr_src,
                                                  const float* __restrict__ b2,
                                                  float* __restrict__ out) {
  int w = threadIdx.x >> 6, lane = threadIdx.x & 63;
  int n = blockIdx.x * 4 + w;
  if (n >= NN) return;
  int beg = offsets[n], end = offsets[n + 1];
  float acc = b2[lane];
  int i = beg;
  for (; i + 1 < end; i += 2) {
    acc += bf2f(h2b[(size_t)csr_src[i] * OUTD + lane]) +
           bf2f(h2b[(size_t)csr_src[i + 1] * OUTD + lane]);
  }
  if (i < end) acc += bf2f(h2b[(size_t)csr_src[i] * OUTD + lane]);
  float q = acc * acc;
#pragma unroll
  for (int off = 32; off > 0; off >>= 1) q += __shfl_xor(q, off);
  float norm = sqrtf(q);
  float scale = 1.f / fmaxf(norm, 1e-12f);
  out[(size_t)n * OUTD + lane] = acc * scale;
}

// ---------------- launch ----------------------------------------------------
extern "C" void kernel_launch(void* const* d_in, const int* in_sizes, int n_in,
                              void* d_out, int out_size, void* d_ws, size_t ws_size,
                              hipStream_t stream) {
  const float* x     = (const float*)d_in[0];
  const int*   edges = (const int*)d_in[1];
  const float* W1    = (const float*)d_in[2];
  const float* b1    = (const float*)d_in[3];
  const float* W2    = (const float*)d_in[4];
  const float* b2    = (const float*)d_in[5];
  const float* gamma = (const float*)d_in[6];
  const float* beta  = (const float*)d_in[7];

  char* ws = (char*)d_ws;
  ushort* h1b    = (ushort*)(ws);                 // 100096*128*2 = 25.6 MB
  float*  agg1   = (float*)(ws + 26000000);       // 100096*128*4 = 51.2 MB
  int*    csr_src= (int*)(ws + 77500000);         // 6.4 MB
  int*    offsets= (int*)(ws + 84000000);         // 100001 ints
  int*    cursor = (int*)(ws + 84400128);         // aliased as cnt during build
  int*    bsum   = (int*)(ws + 84800256);         // 391 ints
  float*  gsum   = (float*)(ws + 84802048);       // 128 f
  float*  gsq    = (float*)(ws + 84802560);       // 128 f
  float*  isg    = (float*)(ws + 84803072);       // 128 f
  float*  bbv    = (float*)(ws + 84803584);       // 128 f
  int*    eflag  = (int*)(ws + 84804096);         // 1 int
  ushort* Wth    = (ushort*)(ws + 84804608);      // 128 KB
  ushort* Wtl    = (ushort*)(ws + 84935680);      // 128 KB
  ushort* h2b    = h1b;                           // reuse (h1b dead after agg1)

  if (ws_size < 85100000) return;  // scratch layout requirement

  hipMemsetAsync(cursor, 0, (NN + 1) * sizeof(int), stream);  // cnt = 0
  hipMemsetAsync(gsum, 0, 1024, stream);                      // gsum+gsq = 0

  k_detect<<<1, 64, 0, stream>>>(edges, eflag);
  k_prepW<<<256, 256, 0, stream>>>(W1, Wth, Wtl);
  k_gemm1m<<<782, 256, 0, stream>>>(x, Wth, Wtl, h1b);
  k_count<<<6250, 256, 0, stream>>>(edges, eflag, cursor);
  k_s1<<<NBLK, 256, 0, stream>>>(cursor, bsum);
  k_s2<<<1, 512, 0, stream>>>(bsum);
  k_s3<<<NBLK, 256, 0, stream>>>(cursor, bsum, offsets, cursor);
  k_scatter<<<6250, 256, 0, stream>>>(edges, eflag, cursor, csr_src);
  k_agg1<<<25000, 256, 0, stream>>>(h1b, offsets, csr_src, b1, agg1);
  k_bnstats<<<782, 256, 0, stream>>>(agg1, gsum, gsq);
  k_bnfin<<<1, 128, 0, stream>>>(gsum, gsq, gamma, beta, isg, bbv);
  k_gemm2<<<782, 256, 0, stream>>>(agg1, W2, isg, bbv, h2b);
  k_agg2norm<<<25000, 256, 0, stream>>>(h2b, offsets, csr_src, b2,
                                        (float*)d_out);
}